// Round 11
// baseline (49.717 us; speedup 1.0000x reference)
//
#include <hip/hip_runtime.h>

#define GATE_SCALE 1.7015f

typedef __attribute__((ext_vector_type(8))) short short8;
typedef __attribute__((ext_vector_type(4))) float f32x4;
typedef __attribute__((ext_vector_type(16))) float f32x16;

__device__ __forceinline__ ushort f2bf(float f) {
    union { float f; unsigned u; } v; v.f = f;
    unsigned u = v.u;
    unsigned r = (u + 0x7FFFu + ((u >> 16) & 1u)) >> 16;
    return (ushort)r;
}

__device__ __forceinline__ void gl2lds16(const void* g, void* l) {
    __builtin_amdgcn_global_load_lds((const __attribute__((address_space(1))) void*)g,
                                     (__attribute__((address_space(3))) void*)l, 16, 0, 0);
}

// ---------------------------------------------------------------------------
// Kernel 1: convert x_cat and W to bf16; tail blocks build antisymmetrized
// complex A: Ac[n][o*8+i][2]
// ---------------------------------------------------------------------------
__global__ void convert_kernel(const float* __restrict__ xr, const float* __restrict__ xi,
                               const float* __restrict__ W,
                               const float* __restrict__ Ar, const float* __restrict__ Ai,
                               ushort* __restrict__ xc, ushort* __restrict__ wb,
                               float* __restrict__ Ac) {
    int bx = blockIdx.x;
    if (bx >= 1024) {
        int v = (bx - 1024) * 256 + threadIdx.x;   // 0..8191
        if (v < 8192) {
            int n = v >> 6, t = v & 63, o = t >> 3, i = t & 7;
            const float* arn = Ar + n * 64;
            const float* ain = Ai + n * 64;
            float a_r = 0.5f * (arn[o * 8 + i] - arn[i * 8 + o]);
            float a_i = 0.5f * (ain[o * 8 + i] + ain[i * 8 + o]);
            Ac[n * 128 + t * 2]     = a_r;
            Ac[n * 128 + t * 2 + 1] = a_i;
        }
        return;
    }
    const int XCV = 2048 * 2048 / 4;
    const int WV  = 1024 * 2048 / 4;
    const int STR = 1024 * 256;
    for (int v = bx * 256 + threadIdx.x; v < XCV + WV; v += STR) {
        float4 f;
        ushort* dst;
        if (v < XCV) {
            int idx = v * 4;
            int m = idx >> 11;
            int k = idx & 2047;
            const float* s = (k < 1024) ? (xr + m * 1024 + k) : (xi + m * 1024 + k - 1024);
            f = *(const float4*)s;
            dst = xc + idx;
        } else {
            int idx = (v - XCV) * 4;
            f = *(const float4*)(W + idx);
            dst = wb + idx;
        }
        ushort4 o;
        o.x = f2bf(f.x); o.y = f2bf(f.y); o.z = f2bf(f.z); o.w = f2bf(f.w);
        *(ushort4*)dst = o;
    }
}

// ---------------------------------------------------------------------------
// Kernel 2: split-K GEMM partials.  zp[kh] = xc[:, kh*1024:+1024] @ wb^T part.
// Tile 128x128, split-K=2 -> 16m x 8n x 2k = 256 blocks (full machine) and
// staged bytes halve: 8*|A| + 16*|B| = 134 MB (was 268 at 64x64 tiles).
// 8 waves (2m x 4n), two 32x32x16 accs/wave, BK=64, ring-4 LDS (128 KB),
// counted vmcnt(8) + raw barrier (R7 schedule), setprio MFMA.
// XCD grouping: x = [n-half | m-half | k-half]; per-XCD unique bytes =
// (8m + 4n)*128*1024*2 = 3.15 MB < 4 MB L2.
// LDS XOR-swizzle via pre-swizzled global source (rule 21), 8 slots/row.
// ---------------------------------------------------------------------------
__launch_bounds__(512, 1)
__global__ void gemm_part_kernel(const ushort* __restrict__ A,   // xc [2048][2048]
                                 const ushort* __restrict__ Bw,  // wb [1024][2048]
                                 float* __restrict__ zp0,        // [2048][1024]
                                 float* __restrict__ zp1) {      // [2048][1024]
    __shared__ __align__(16) ushort lA[4][128 * 64];   // 4 x 16 KB
    __shared__ __align__(16) ushort lB[4][128 * 64];   // 4 x 16 KB
    const int tid = threadIdx.x;
    const int lane = tid & 63;
    const int wid = tid >> 6;                 // 0..7
    // 256 blocks = 8 XCDs x 32. x bits: k-half = x&1, m-half = (x>>1)&1,
    // n-half = x>>2. local l: m-oct = l&7, n-quad = l>>3.
    const int bid = blockIdx.x;
    const int x = bid & 7, l = bid >> 3;      // xcd, local 0..31
    const int kh = x & 1;
    const int m0 = (((x >> 1) & 1) * 8 + (l & 7)) * 128;
    const int n0 = ((x >> 2) * 4 + (l >> 3)) * 128;
    const int k0b = kh * 1024;
    const int wm = wid >> 2, wn = wid & 3;    // 2m x 4n waves
    const int lo = lane & 31, hi = lane >> 5, lo3 = lane & 7;
    const int arow0 = wm * 64 + lo;           // m-sub 0 row
    const int brow = wn * 32 + lo;
    const int r7 = lo & 7;                    // row&7 for all frag rows

    f32x16 acc0 = {}, acc1 = {};

    // LDS 16B-slot s of row holds global k-chunk s ^ (row&7).
    #define STAGE(buf, k0)                                                          \
        {                                                                           \
            _Pragma("unroll")                                                       \
            for (int q = 0; q < 2; ++q) {                                           \
                int c = q * 512 + tid;                                              \
                int row = c >> 3, ks = (c & 7) ^ (row & 7);                         \
                gl2lds16(&A[(m0 + row) * 2048 + (k0) + ks * 8], &lA[buf][c * 8]);   \
            }                                                                       \
            _Pragma("unroll")                                                       \
            for (int q = 0; q < 2; ++q) {                                           \
                int c = q * 512 + tid;                                              \
                int row = c >> 3, ks = (c & 7) ^ (row & 7);                         \
                gl2lds16(&Bw[(n0 + row) * 2048 + (k0) + ks * 8], &lB[buf][c * 8]);  \
            }                                                                       \
        }

    // Counted vmcnt: 4 gl2lds/thread/stage, depth-3 prefetch -> wait at 8.
    #define TILE(t, vmstr, do_stage)                                               \
        {                                                                           \
            asm volatile("s_waitcnt vmcnt(" vmstr ")" ::: "memory");                \
            __builtin_amdgcn_s_barrier();                                           \
            const int b = (t) & 3;                                                  \
            short8 af0[4], af1[4], bf[4];                                           \
            _Pragma("unroll")                                                       \
            for (int kk = 0; kk < 4; ++kk) {                                        \
                const int ch = ((2 * kk + hi) ^ r7) << 3;                           \
                af0[kk] = *(const short8*)&lA[b][arow0 * 64 + ch];                  \
                af1[kk] = *(const short8*)&lA[b][(arow0 + 32) * 64 + ch];           \
                bf[kk]  = *(const short8*)&lB[b][brow * 64 + ch];                   \
            }                                                                       \
            if (do_stage) STAGE((((t) + 3) & 3), k0b + ((t) + 3) * 64);             \
            __builtin_amdgcn_s_setprio(1);                                          \
            _Pragma("unroll")                                                       \
            for (int kk = 0; kk < 4; ++kk) {                                        \
                acc0 = __builtin_amdgcn_mfma_f32_32x32x16_bf16(af0[kk], bf[kk], acc0, 0, 0, 0); \
                acc1 = __builtin_amdgcn_mfma_f32_32x32x16_bf16(af1[kk], bf[kk], acc1, 0, 0, 0); \
            }                                                                       \
            __builtin_amdgcn_s_setprio(0);                                          \
        }

    STAGE(0, k0b);
    STAGE(1, k0b + 64);
    STAGE(2, k0b + 128);
    for (int t = 0; t < 13; ++t) TILE(t, "8", true);
    TILE(13, "8", false);
    TILE(14, "4", false);
    TILE(15, "0", false);
    #undef TILE
    #undef STAGE

    // Write raw f32 partials. C/D col = lane&31, row = (r&3)+8*(r>>2)+4*hi.
    float* __restrict__ zp = kh ? zp1 : zp0;
    const int ncol = n0 + wn * 32 + lo;
    #pragma unroll
    for (int s = 0; s < 2; ++s) {
        const f32x16 a = s ? acc1 : acc0;
        const int mb = m0 + wm * 64 + s * 32;
        #pragma unroll
        for (int r = 0; r < 16; ++r) {
            const int mrow = mb + (r & 3) + 8 * (r >> 2) + 4 * hi;
            zp[mrow * 1024 + ncol] = a[r];
        }
    }
}

// ---------------------------------------------------------------------------
// Kernel 2b: z = zp0 + zp1 + bias; gate = sigmoid(z*1.7015); 8-col mean -> g
// ---------------------------------------------------------------------------
__global__ void reduce_kernel(const float* __restrict__ zp0, const float* __restrict__ zp1,
                              const float* __restrict__ bias,
                              float* __restrict__ g) {          // [2048][128]
    const int idx = blockIdx.x * 256 + threadIdx.x;             // 0..262143
    const int mrow = idx >> 7, gc = idx & 127;
    const float4* p0 = (const float4*)&zp0[mrow * 1024 + gc * 8];
    const float4* p1 = (const float4*)&zp1[mrow * 1024 + gc * 8];
    const float4* bv = (const float4*)&bias[gc * 8];
    float s = 0.f;
    #pragma unroll
    for (int h = 0; h < 2; ++h) {
        float4 a = p0[h], b = p1[h], c = bv[h];
        float z0 = (a.x + b.x + c.x) * GATE_SCALE;
        float z1 = (a.y + b.y + c.y) * GATE_SCALE;
        float z2 = (a.z + b.z + c.z) * GATE_SCALE;
        float z3 = (a.w + b.w + c.w) * GATE_SCALE;
        s += 1.0f / (1.0f + __expf(-z0));
        s += 1.0f / (1.0f + __expf(-z1));
        s += 1.0f / (1.0f + __expf(-z2));
        s += 1.0f / (1.0f + __expf(-z3));
    }
    g[mrow * 128 + gc] = s * 0.125f;
}

// ---------------------------------------------------------------------------
// Kernel 3: apply via Horner, zero LDS. Two lanes per site: lane h owns
// output rows h*4..h*4+3; A-block (4x8 complex) lives in 64 VGPRs, gathered
// once per block from L2-resident Ac. w-half exchanged via __shfl_xor(.,1)
// (DPP). x loads perfectly coalesced float4 (d = lane*4).
//   out = x + A(c1 x + A(c2 x + A(c3 x + A(c4 x)))),  c_k = 2(-g)^k
// ---------------------------------------------------------------------------
__launch_bounds__(256)
__global__ void apply_kernel(const float* __restrict__ xr, const float* __restrict__ xi,
                             const float* __restrict__ g,   // [2048][128]
                             const float* __restrict__ Ac,  // [128][64][2]
                             float* __restrict__ outr, float* __restrict__ outi) {
    const int tid = threadIdx.x;
    const int lane = tid & 63;
    const int wv = tid >> 6;
    const int nl = lane >> 1, h = lane & 1;
    const int n = blockIdx.x * 32 + nl;
    const int mbase = blockIdx.y * 8 + wv * 2;

    float Ar_[4][8], Ai_[4][8];
    const float* An = Ac + n * 128;
    #pragma unroll
    for (int r = 0; r < 4; ++r) {
        const int o = h * 4 + r;
        #pragma unroll
        for (int p = 0; p < 2; ++p) {
            float4 f = *(const float4*)&An[o * 16 + h * 8 + p * 4];
            Ar_[r][p * 2]     = f.x;  Ai_[r][p * 2]     = f.y;
            Ar_[r][p * 2 + 1] = f.z;  Ai_[r][p * 2 + 1] = f.w;
        }
        #pragma unroll
        for (int p = 0; p < 2; ++p) {
            float4 f = *(const float4*)&An[o * 16 + (1 - h) * 8 + p * 4];
            Ar_[r][4 + p * 2]     = f.x;  Ai_[r][4 + p * 2]     = f.y;
            Ar_[r][4 + p * 2 + 1] = f.z;  Ai_[r][4 + p * 2 + 1] = f.w;
        }
    }

    #define CMV()                                                                   \
        {                                                                           \
            float pwr[4], pwi[4];                                                   \
            _Pragma("unroll")                                                       \
            for (int k2 = 0; k2 < 4; ++k2) {                                        \
                pwr[k2] = __shfl_xor(wr[k2], 1);                                    \
                pwi[k2] = __shfl_xor(wi[k2], 1);                                    \
            }                                                                       \
            _Pragma("unroll")                                                       \
            for (int r = 0; r < 4; ++r) {                                           \
                float sr = 0.f, si = 0.f;                                           \
                _Pragma("unroll")                                                   \
                for (int jj = 0; jj < 4; ++jj) {                                    \
                    sr += Ar_[r][jj] * wr[jj]      - Ai_[r][jj] * wi[jj];           \
                    si += Ar_[r][jj] * wi[jj]      + Ai_[r][jj] * wr[jj];           \
                    sr += Ar_[r][4 + jj] * pwr[jj] - Ai_[r][4 + jj] * pwi[jj];      \
                    si += Ar_[r][4 + jj] * pwi[jj] + Ai_[r][4 + jj] * pwr[jj];      \
                }                                                                   \
                tr[r] = sr; ti[r] = si;                                             \
            }                                                                       \
        }

    #pragma unroll
    for (int mi = 0; mi < 2; ++mi) {
        const int m = mbase + mi;
        const int d = n * 8 + h * 4;
        const float4 fvr = *(const float4*)&xr[m * 1024 + d];
        const float4 fvi = *(const float4*)&xi[m * 1024 + d];
        float vr[4] = {fvr.x, fvr.y, fvr.z, fvr.w};
        float vi[4] = {fvi.x, fvi.y, fvi.z, fvi.w};
        const float gv = g[m * 128 + n];
        const float c1 = -2.f * gv, c2 = -c1 * gv, c3 = -c2 * gv, c4 = -c3 * gv;
        float wr[4], wi[4], tr[4], ti[4];

        #pragma unroll
        for (int r = 0; r < 4; ++r) { wr[r] = c4 * vr[r]; wi[r] = c4 * vi[r]; }
        CMV();
        #pragma unroll
        for (int r = 0; r < 4; ++r) { wr[r] = c3 * vr[r] + tr[r]; wi[r] = c3 * vi[r] + ti[r]; }
        CMV();
        #pragma unroll
        for (int r = 0; r < 4; ++r) { wr[r] = c2 * vr[r] + tr[r]; wi[r] = c2 * vi[r] + ti[r]; }
        CMV();
        #pragma unroll
        for (int r = 0; r < 4; ++r) { wr[r] = c1 * vr[r] + tr[r]; wi[r] = c1 * vi[r] + ti[r]; }
        CMV();

        float4 s0 = {vr[0] + tr[0], vr[1] + tr[1], vr[2] + tr[2], vr[3] + tr[3]};
        float4 s1 = {vi[0] + ti[0], vi[1] + ti[1], vi[2] + ti[2], vi[3] + ti[3]};
        *(float4*)&outr[m * 1024 + d] = s0;
        *(float4*)&outi[m * 1024 + d] = s1;
    }
    #undef CMV
}

// ---------------------------------------------------------------------------
extern "C" void kernel_launch(void* const* d_in, const int* in_sizes, int n_in,
                              void* d_out, int out_size, void* d_ws, size_t ws_size,
                              hipStream_t stream) {
    const float* xr = (const float*)d_in[0];
    const float* xi = (const float*)d_in[1];
    const float* Ar = (const float*)d_in[2];
    const float* Ai = (const float*)d_in[3];
    const float* W  = (const float*)d_in[4];
    const float* bg = (const float*)d_in[5];
    float* out = (float*)d_out;

    char* ws = (char*)d_ws;
    ushort* xc  = (ushort*)(ws);                 // 8388608 B
    ushort* wb  = (ushort*)(ws + 8388608);       // 4194304 B
    float*  g   = (float*) (ws + 12582912);      // 1048576 B
    float*  Ac  = (float*) (ws + 13631488);      // 65536 B
    float*  zp0 = (float*) (ws + 13697024);      // 8388608 B
    float*  zp1 = (float*) (ws + 22085632);      // 8388608 B

    hipLaunchKernelGGL(convert_kernel, dim3(1056), dim3(256), 0, stream,
                       xr, xi, W, Ar, Ai, xc, wb, Ac);
    hipLaunchKernelGGL(gemm_part_kernel, dim3(256), dim3(512), 0, stream, xc, wb, zp0, zp1);
    hipLaunchKernelGGL(reduce_kernel, dim3(1024), dim3(256), 0, stream, zp0, zp1, bg, g);
    hipLaunchKernelGGL(apply_kernel, dim3(4, 256), dim3(256), 0, stream,
                       xr, xi, g, Ac, out, out + 2 * 1024 * 1024);
}

// Round 12
// 38.993 us; speedup vs baseline: 1.2750x; 1.2750x over previous
//
#include <hip/hip_runtime.h>

#define GATE_SCALE 1.7015f
#define SX 32.0f
#define SW 1024.0f
#define DESCALE 3.0517578125e-05f   // 1/(SX*SW) = 2^-15

typedef __attribute__((ext_vector_type(4))) int   v4i;
typedef __attribute__((ext_vector_type(16))) int  v16i;

__device__ __forceinline__ void gl2lds16(const void* g, void* l) {
    __builtin_amdgcn_global_load_lds((const __attribute__((address_space(1))) void*)g,
                                     (__attribute__((address_space(3))) void*)l, 16, 0, 0);
}

__device__ __forceinline__ int q8(float v, float s) {
    int q = __float2int_rn(v * s);
    return q < -127 ? -127 : (q > 127 ? 127 : q);
}

// ---------------------------------------------------------------------------
// Kernel 1: quantize x_cat and W to int8; tail blocks build antisymmetrized
// complex A: Ac[n][o*8+i][2]
// ---------------------------------------------------------------------------
__global__ void convert_kernel(const float* __restrict__ xr, const float* __restrict__ xi,
                               const float* __restrict__ W,
                               const float* __restrict__ Ar, const float* __restrict__ Ai,
                               signed char* __restrict__ xq, signed char* __restrict__ wq,
                               float* __restrict__ Ac) {
    int bx = blockIdx.x;
    if (bx >= 1024) {
        int v = (bx - 1024) * 256 + threadIdx.x;   // 0..8191
        if (v < 8192) {
            int n = v >> 6, t = v & 63, o = t >> 3, i = t & 7;
            const float* arn = Ar + n * 64;
            const float* ain = Ai + n * 64;
            float a_r = 0.5f * (arn[o * 8 + i] - arn[i * 8 + o]);
            float a_i = 0.5f * (ain[o * 8 + i] + ain[i * 8 + o]);
            Ac[n * 128 + t * 2]     = a_r;
            Ac[n * 128 + t * 2 + 1] = a_i;
        }
        return;
    }
    const int XCV = 2048 * 2048 / 4;   // float4 groups for x_cat
    const int WV  = 1024 * 2048 / 4;
    const int STR = 1024 * 256;
    for (int v = bx * 256 + threadIdx.x; v < XCV + WV; v += STR) {
        float4 f;
        signed char* dst;
        float s;
        if (v < XCV) {
            int idx = v * 4;
            int m = idx >> 11;
            int k = idx & 2047;
            const float* src = (k < 1024) ? (xr + m * 1024 + k) : (xi + m * 1024 + k - 1024);
            f = *(const float4*)src;
            dst = xq + idx;
            s = SX;
        } else {
            int idx = (v - XCV) * 4;
            f = *(const float4*)(W + idx);
            dst = wq + idx;
            s = SW;
        }
        int a = q8(f.x, s), b = q8(f.y, s), c = q8(f.z, s), d = q8(f.w, s);
        unsigned int packed = (a & 0xFF) | ((b & 0xFF) << 8) | ((c & 0xFF) << 16)
                            | ((unsigned)(d & 0xFF) << 24);
        *(unsigned int*)dst = packed;
    }
}

// ---------------------------------------------------------------------------
// Kernel 2: i8 GEMM gate = sigmoid((x@W^T)*DESCALE + b)*1.7015 -> 8-col mean
// Tile 64x64, BK=128 BYTES (16 phases), 4 waves (2x2), one 32x32x32_i8
// acc/wave (i32, exact). Grid 512 = 2 blocks/CU. Ring-4 LDS (64 KB), counted
// vmcnt(8) + raw barrier (R7 schedule, byte-identical LDS layout), setprio.
// Staged bytes: 16*|xq| + 32*|wq| = 67 MB (half of bf16).
// Fragment k-order correctness: A and B use identical slot->k addressing ->
// any consistent bijection contracts correctly (row/col = lane&31; C/D map
// is the verified dtype-independent one).
// LDS XOR-swizzle via pre-swizzled global source (rule 21), 8 chunks/row.
// ---------------------------------------------------------------------------
__launch_bounds__(256, 2)
__global__ void gemm_gate_kernel(const signed char* __restrict__ A,   // xq [2048][2048]
                                 const signed char* __restrict__ Bw,  // wq [1024][2048]
                                 const float* __restrict__ bias,      // [1024]
                                 float* __restrict__ g) {             // [2048][128]
    __shared__ __align__(16) signed char lA[4][64 * 128];   // 4 x 8 KB
    __shared__ __align__(16) signed char lB[4][64 * 128];   // 4 x 8 KB
    const int tid = threadIdx.x;
    const int lane = tid & 63;
    const int wid = tid >> 6;                 // 0..3
    // XCD-rectangle swizzle: 512 blocks = 8 XCDs x 64; XCD x = bid&7 owns
    // m-panels [(x&3)*8,+8) x n-panels [(x>>2)*8,+8) (panels of 64).
    const int bid = blockIdx.x;
    const int x = bid & 7, l = bid >> 3;
    const int m0 = ((x & 3) * 8 + (l & 7)) * 64;
    const int n0 = ((x >> 2) * 8 + (l >> 3)) * 64;
    const int wr = wid >> 1, wc = wid & 1;
    const int lo = lane & 31, hi = lane >> 5, lo3 = lane & 7;
    const int arow = wr * 32 + lo, brow = wc * 32 + lo;
    const int ar7 = arow & 7, br7 = brow & 7;

    v16i acc = {};

    // Rows are 128 B = 8 x 16B chunks; chunk s of row holds global byte-chunk
    // s ^ (row&7). Row stride in global memory = 2048 B for both A and B.
    #define STAGE(buf, k0)                                                          \
        {                                                                           \
            _Pragma("unroll")                                                       \
            for (int q = 0; q < 2; ++q) {                                           \
                int c = q * 256 + tid;                                              \
                int row = c >> 3, ks = (c & 7) ^ (row & 7);                         \
                gl2lds16(&A[(m0 + row) * 2048 + (k0) + ks * 16], &lA[buf][c * 16]); \
            }                                                                       \
            _Pragma("unroll")                                                       \
            for (int q = 0; q < 2; ++q) {                                           \
                int c = q * 256 + tid;                                              \
                int row = c >> 3, ks = (c & 7) ^ (row & 7);                         \
                gl2lds16(&Bw[(n0 + row) * 2048 + (k0) + ks * 16], &lB[buf][c * 16]);\
            }                                                                       \
        }

    // Counted vmcnt: 4 gl2lds/thread/stage, depth-3 prefetch -> wait at 8.
    #define TILE(t, vmstr, do_stage)                                               \
        {                                                                           \
            asm volatile("s_waitcnt vmcnt(" vmstr ")" ::: "memory");                \
            __builtin_amdgcn_s_barrier();                                           \
            const int b = (t) & 3;                                                  \
            v4i af[4], bf[4];                                                       \
            _Pragma("unroll")                                                       \
            for (int kk = 0; kk < 4; ++kk) {                                        \
                const int ch = ((2 * kk + hi) ^ ar7) << 4;                          \
                const int chb = ((2 * kk + hi) ^ br7) << 4;                         \
                af[kk] = *(const v4i*)&lA[b][arow * 128 + ch];                      \
                bf[kk] = *(const v4i*)&lB[b][brow * 128 + chb];                     \
            }                                                                       \
            if (do_stage) STAGE((((t) + 3) & 3), ((t) + 3) * 128);                  \
            __builtin_amdgcn_s_setprio(1);                                          \
            _Pragma("unroll")                                                       \
            for (int kk = 0; kk < 4; ++kk)                                          \
                acc = __builtin_amdgcn_mfma_i32_32x32x32_i8(af[kk], bf[kk], acc, 0, 0, 0); \
            __builtin_amdgcn_s_setprio(0);                                          \
        }

    STAGE(0, 0);
    STAGE(1, 128);
    STAGE(2, 256);
    for (int t = 0; t < 13; ++t) TILE(t, "8", true);
    TILE(13, "8", false);
    TILE(14, "4", false);
    TILE(15, "0", false);
    #undef TILE
    #undef STAGE

    // Epilogue: C/D col = lane&31 (n), row = (r&3)+8*(r>>2)+4*hi (m-local).
    const int ncol = n0 + wc * 32 + lo;
    const float bv = bias[ncol];
    const int gcol = ncol >> 3;
    #pragma unroll
    for (int r = 0; r < 16; ++r) {
        const int mrow = m0 + wr * 32 + (r & 3) + 8 * (r >> 2) + 4 * hi;
        float z = ((float)acc[r] * DESCALE + bv) * GATE_SCALE;
        float gate = 1.0f / (1.0f + __expf(-z));
        gate += __shfl_xor(gate, 1);
        gate += __shfl_xor(gate, 2);
        gate += __shfl_xor(gate, 4);
        if (lo3 == 0)
            g[mrow * 128 + gcol] = gate * 0.125f;
    }
}

// ---------------------------------------------------------------------------
// Kernel 3: apply via Horner, zero LDS. Two lanes per site: lane h owns
// output rows h*4..h*4+3; A-block (4x8 complex) lives in 64 VGPRs, gathered
// once per block from L2-resident Ac. w-half exchanged via __shfl_xor(.,1)
// (DPP). x loads perfectly coalesced float4 (d = lane*4).
//   out = x + A(c1 x + A(c2 x + A(c3 x + A(c4 x)))),  c_k = 2(-g)^k
// ---------------------------------------------------------------------------
__launch_bounds__(256)
__global__ void apply_kernel(const float* __restrict__ xr, const float* __restrict__ xi,
                             const float* __restrict__ g,   // [2048][128]
                             const float* __restrict__ Ac,  // [128][64][2]
                             float* __restrict__ outr, float* __restrict__ outi) {
    const int tid = threadIdx.x;
    const int lane = tid & 63;
    const int wv = tid >> 6;
    const int nl = lane >> 1, h = lane & 1;
    const int n = blockIdx.x * 32 + nl;
    const int mbase = blockIdx.y * 8 + wv * 2;

    float Ar_[4][8], Ai_[4][8];
    const float* An = Ac + n * 128;
    #pragma unroll
    for (int r = 0; r < 4; ++r) {
        const int o = h * 4 + r;
        #pragma unroll
        for (int p = 0; p < 2; ++p) {
            float4 f = *(const float4*)&An[o * 16 + h * 8 + p * 4];
            Ar_[r][p * 2]     = f.x;  Ai_[r][p * 2]     = f.y;
            Ar_[r][p * 2 + 1] = f.z;  Ai_[r][p * 2 + 1] = f.w;
        }
        #pragma unroll
        for (int p = 0; p < 2; ++p) {
            float4 f = *(const float4*)&An[o * 16 + (1 - h) * 8 + p * 4];
            Ar_[r][4 + p * 2]     = f.x;  Ai_[r][4 + p * 2]     = f.y;
            Ar_[r][4 + p * 2 + 1] = f.z;  Ai_[r][4 + p * 2 + 1] = f.w;
        }
    }

    #define CMV()                                                                   \
        {                                                                           \
            float pwr[4], pwi[4];                                                   \
            _Pragma("unroll")                                                       \
            for (int k2 = 0; k2 < 4; ++k2) {                                        \
                pwr[k2] = __shfl_xor(wr[k2], 1);                                    \
                pwi[k2] = __shfl_xor(wi[k2], 1);                                    \
            }                                                                       \
            _Pragma("unroll")                                                       \
            for (int r = 0; r < 4; ++r) {                                           \
                float sr = 0.f, si = 0.f;                                           \
                _Pragma("unroll")                                                   \
                for (int jj = 0; jj < 4; ++jj) {                                    \
                    sr += Ar_[r][jj] * wr[jj]      - Ai_[r][jj] * wi[jj];           \
                    si += Ar_[r][jj] * wi[jj]      + Ai_[r][jj] * wr[jj];           \
                    sr += Ar_[r][4 + jj] * pwr[jj] - Ai_[r][4 + jj] * pwi[jj];      \
                    si += Ar_[r][4 + jj] * pwi[jj] + Ai_[r][4 + jj] * pwr[jj];      \
                }                                                                   \
                tr[r] = sr; ti[r] = si;                                             \
            }                                                                       \
        }

    #pragma unroll
    for (int mi = 0; mi < 2; ++mi) {
        const int m = mbase + mi;
        const int d = n * 8 + h * 4;
        const float4 fvr = *(const float4*)&xr[m * 1024 + d];
        const float4 fvi = *(const float4*)&xi[m * 1024 + d];
        float vr[4] = {fvr.x, fvr.y, fvr.z, fvr.w};
        float vi[4] = {fvi.x, fvi.y, fvi.z, fvi.w};
        const float gv = g[m * 128 + n];
        const float c1 = -2.f * gv, c2 = -c1 * gv, c3 = -c2 * gv, c4 = -c3 * gv;
        float wr[4], wi[4], tr[4], ti[4];

        #pragma unroll
        for (int r = 0; r < 4; ++r) { wr[r] = c4 * vr[r]; wi[r] = c4 * vi[r]; }
        CMV();
        #pragma unroll
        for (int r = 0; r < 4; ++r) { wr[r] = c3 * vr[r] + tr[r]; wi[r] = c3 * vi[r] + ti[r]; }
        CMV();
        #pragma unroll
        for (int r = 0; r < 4; ++r) { wr[r] = c2 * vr[r] + tr[r]; wi[r] = c2 * vi[r] + ti[r]; }
        CMV();
        #pragma unroll
        for (int r = 0; r < 4; ++r) { wr[r] = c1 * vr[r] + tr[r]; wi[r] = c1 * vi[r] + ti[r]; }
        CMV();

        float4 s0 = {vr[0] + tr[0], vr[1] + tr[1], vr[2] + tr[2], vr[3] + tr[3]};
        float4 s1 = {vi[0] + ti[0], vi[1] + ti[1], vi[2] + ti[2], vi[3] + ti[3]};
        *(float4*)&outr[m * 1024 + d] = s0;
        *(float4*)&outi[m * 1024 + d] = s1;
    }
    #undef CMV
}

// ---------------------------------------------------------------------------
extern "C" void kernel_launch(void* const* d_in, const int* in_sizes, int n_in,
                              void* d_out, int out_size, void* d_ws, size_t ws_size,
                              hipStream_t stream) {
    const float* xr = (const float*)d_in[0];
    const float* xi = (const float*)d_in[1];
    const float* Ar = (const float*)d_in[2];
    const float* Ai = (const float*)d_in[3];
    const float* W  = (const float*)d_in[4];
    const float* bg = (const float*)d_in[5];
    float* out = (float*)d_out;

    char* ws = (char*)d_ws;
    signed char* xq = (signed char*)(ws);            // 2048*2048   = 4194304 B
    signed char* wq = (signed char*)(ws + 4194304);  // 1024*2048   = 2097152 B
    float*  g  = (float*)(ws + 6291456);             // 2048*128*4  = 1048576 B
    float*  Ac = (float*)(ws + 7340032);             // 128*128*4   = 65536 B

    hipLaunchKernelGGL(convert_kernel, dim3(1056), dim3(256), 0, stream,
                       xr, xi, W, Ar, Ai, xq, wq, Ac);
    hipLaunchKernelGGL(gemm_gate_kernel, dim3(512), dim3(256), 0, stream, xq, wq, bg, g);
    hipLaunchKernelGGL(apply_kernel, dim3(4, 256), dim3(256), 0, stream,
                       xr, xi, g, Ac, out, out + 2 * 1024 * 1024);
}